// Round 11
// baseline (359.787 us; speedup 1.0000x reference)
//
#include <hip/hip_runtime.h>

#define NSUB 20000
#define NREG 100000
#define NEDGE 600000
#define DIM 128
#define LAY 2
#define NOUT 2

// ---- atomic-free CSR build geometry ----
#define NB_A 256             // chunk blocks per edge type
#define CHK 2344             // ceil(NEDGE / NB_A)
#define NBKT_S 79            // subject coarse buckets (79*256 = 20224 >= NSUB)
#define NBKT_R 391           // region  coarse buckets (391*256 = 100096 >= NREG)
#define NBKT_MAX 391
#define NBKT_TOT (NBKT_S + 2 * NBKT_R)   // 861

#define CVT_BLKS 15000       // (NSUB+NREG)*DIM/4/256

typedef __attribute__((ext_vector_type(8))) short bf16x8;
typedef __attribute__((ext_vector_type(8))) unsigned short u16x8;
typedef __attribute__((ext_vector_type(4))) unsigned short u16x4;
typedef __attribute__((ext_vector_type(4))) float f32x4;

__device__ __forceinline__ float bf2f(unsigned short u) {
    return __uint_as_float(((unsigned)u) << 16);
}
__device__ __forceinline__ unsigned short f2bf(float f) {
    unsigned x = __float_as_uint(f);
    unsigned r = ((x >> 16) & 1u) + 0x7fffu;   // RNE
    return (unsigned short)((x + r) >> 16);
}

// ---------------------------------------------------------------------------
// MFMA GEMM body, 128-row tile (proven r6 structure).
// ---------------------------------------------------------------------------
__device__ __forceinline__ void gemm_body(
    const unsigned short* A0, const unsigned short* Wp0,
    const unsigned short* A1, const unsigned short* Wp1,
    const unsigned short* agg, const float* b0, const float* b1,
    unsigned short* out, int M, int rowBase, unsigned short* sO)
{
    const int t = threadIdx.x, wave = t >> 6, lane = t & 63;
    int ar0 = rowBase + wave * 32 + (lane & 15);
    int ar1 = ar0 + 16;
    if (ar0 >= M) ar0 = M - 1;
    if (ar1 >= M) ar1 = M - 1;
    const bf16x8* Ap0g0 = (const bf16x8*)(A0 + (size_t)ar0 * DIM + (lane >> 4) * 8);
    const bf16x8* Ap0g1 = (const bf16x8*)(A0 + (size_t)ar1 * DIM + (lane >> 4) * 8);
    const bf16x8* Bp0 = (const bf16x8*)Wp0;
    f32x4 acc[2][8] = {};
    if (A1) {
        const bf16x8* Ap1g0 = (const bf16x8*)(A1 + (size_t)ar0 * DIM + (lane >> 4) * 8);
        const bf16x8* Ap1g1 = (const bf16x8*)(A1 + (size_t)ar1 * DIM + (lane >> 4) * 8);
        const bf16x8* Bp1 = (const bf16x8*)Wp1;
#pragma unroll
        for (int ks = 0; ks < 4; ++ks) {
            const bf16x8 a00 = Ap0g0[ks * 4];
            const bf16x8 a01 = Ap0g1[ks * 4];
            const bf16x8 a10 = Ap1g0[ks * 4];
            const bf16x8 a11 = Ap1g1[ks * 4];
#pragma unroll
            for (int tn = 0; tn < 8; ++tn) {
                const bf16x8 bA = Bp0[(tn * 4 + ks) * 64 + lane];
                const bf16x8 bB = Bp1[(tn * 4 + ks) * 64 + lane];
                acc[0][tn] = __builtin_amdgcn_mfma_f32_16x16x32_bf16(a00, bA, acc[0][tn], 0, 0, 0);
                acc[1][tn] = __builtin_amdgcn_mfma_f32_16x16x32_bf16(a01, bA, acc[1][tn], 0, 0, 0);
                acc[0][tn] = __builtin_amdgcn_mfma_f32_16x16x32_bf16(a10, bB, acc[0][tn], 0, 0, 0);
                acc[1][tn] = __builtin_amdgcn_mfma_f32_16x16x32_bf16(a11, bB, acc[1][tn], 0, 0, 0);
            }
        }
    } else {
#pragma unroll
        for (int ks = 0; ks < 4; ++ks) {
            const bf16x8 a00 = Ap0g0[ks * 4];
            const bf16x8 a01 = Ap0g1[ks * 4];
#pragma unroll
            for (int tn = 0; tn < 8; ++tn) {
                const bf16x8 bA = Bp0[(tn * 4 + ks) * 64 + lane];
                acc[0][tn] = __builtin_amdgcn_mfma_f32_16x16x32_bf16(a00, bA, acc[0][tn], 0, 0, 0);
                acc[1][tn] = __builtin_amdgcn_mfma_f32_16x16x32_bf16(a01, bA, acc[1][tn], 0, 0, 0);
            }
        }
    }
    const int col0 = lane & 15;
#pragma unroll
    for (int g = 0; g < 2; ++g) {
        const int lrow0 = wave * 32 + g * 16 + (lane >> 4) * 4;
#pragma unroll
        for (int tn = 0; tn < 8; ++tn) {
            const int col = tn * 16 + col0;
            float bv = 0.0f;
            if (b0) bv += b0[col];
            if (b1) bv += b1[col];
#pragma unroll
            for (int r = 0; r < 4; ++r) {
                float v = acc[g][tn][r] + bv;
                if (agg) {
                    int rr = rowBase + lrow0 + r;
                    if (rr >= M) rr = M - 1;
                    v += bf2f(agg[(size_t)rr * DIM + col]);
                }
                sO[(lrow0 + r) * 132 + col] = f2bf(v);
            }
        }
    }
    __syncthreads();
#pragma unroll
    for (int p = 0; p < 2; ++p) {
        const int lr = p * 64 + (t >> 2), lc = (t & 3) * 32;
        const int grow = rowBase + lr;
        if (grow < M) {
            unsigned short* po = out + (size_t)grow * DIM + lc;
            const unsigned short* ps = sO + lr * 132 + lc;
#pragma unroll
            for (int j = 0; j < 8; ++j)
                *(u16x4*)(po + j * 4) = *(const u16x4*)(ps + j * 4);
        }
    }
}

__global__ __launch_bounds__(256) void gemm_fused(
    const unsigned short* __restrict__ A0, const unsigned short* __restrict__ Wp0,
    const unsigned short* __restrict__ A1, const unsigned short* __restrict__ Wp1,
    const unsigned short* __restrict__ agg,
    const float* __restrict__ b0, const float* __restrict__ b1,
    unsigned short* __restrict__ out, int M)
{
    __shared__ unsigned short sO[128 * 132];
    gemm_body(A0, Wp0, A1, Wp1, agg, b0, b1, out, M, blockIdx.x * 128, sO);
}

__global__ __launch_bounds__(256) void gemm_pair(
    const unsigned short* As0, const unsigned short* Ws0,
    const unsigned short* As1, const unsigned short* Ws1,
    const float* bs0, unsigned short* outS, int Ms,
    const unsigned short* Ar0, const unsigned short* Wr0,
    const unsigned short* Ar1, const unsigned short* Wr1,
    const unsigned short* aggr, const float* br0, const float* br1,
    unsigned short* outR, int Mr, int split)
{
    __shared__ unsigned short sO[128 * 132];
    const int bid = blockIdx.x;
    if (bid < split)
        gemm_body(As0, Ws0, As1, Ws1, nullptr, bs0, nullptr, outS, Ms, bid * 128, sO);
    else
        gemm_body(Ar0, Wr0, Ar1, Wr1, aggr, br0, br1, outR, Mr, (bid - split) * 128, sO);
}

// ---------------------------------------------------------------------------
// Atomic-free CSR build: two-level counting sort per edge type (r8 proven).
// ---------------------------------------------------------------------------
__global__ __launch_bounds__(256) void histA(
    const int* __restrict__ d0, const int* __restrict__ d1,
    const int* __restrict__ d2, int* __restrict__ cntA)
{
    __shared__ int hist[NBKT_MAX];
    const int b = blockIdx.x;
    const int type = b / NB_A;
    const int blk = b - type * NB_A;
    const int nbkt = (type == 0) ? NBKT_S : NBKT_R;
    const int* dst = (type == 0) ? d0 : (type == 1) ? d1 : d2;
    for (int i = threadIdx.x; i < nbkt; i += 256) hist[i] = 0;
    __syncthreads();
    const int e1 = min((blk + 1) * CHK, NEDGE);
    for (int e = blk * CHK + threadIdx.x; e < e1; e += 256)
        atomicAdd(&hist[dst[e] >> 8], 1);
    __syncthreads();
    int* row = cntA + ((size_t)type * NB_A + blk) * NBKT_MAX;
    for (int i = threadIdx.x; i < nbkt; i += 256) row[i] = hist[i];
}

__global__ __launch_bounds__(256) void colscan(
    const int* __restrict__ cntA, int* __restrict__ blkpfx, int* __restrict__ binTotal)
{
    __shared__ int s[NB_A];
    const int gb = blockIdx.x;
    int type, bin;
    if (gb < NBKT_S)              { type = 0; bin = gb; }
    else if (gb < NBKT_S + NBKT_R){ type = 1; bin = gb - NBKT_S; }
    else                          { type = 2; bin = gb - NBKT_S - NBKT_R; }
    const int t = threadIdx.x;
    const size_t idx = ((size_t)type * NB_A + t) * NBKT_MAX + bin;
    const int own = cntA[idx];
    s[t] = own;
    __syncthreads();
#pragma unroll
    for (int off = 1; off < NB_A; off <<= 1) {
        const int u = (t >= off) ? s[t - off] : 0;
        __syncthreads();
        s[t] += u;
        __syncthreads();
    }
    blkpfx[idx] = s[t] - own;
    if (t == NB_A - 1) binTotal[gb] = s[t];
}

__global__ void binscan(const int* __restrict__ binTotal, int* __restrict__ bucketStart)
{
    __shared__ int s[512];
    const int ty = blockIdx.x;
    const int start = (ty == 0) ? 0 : (ty == 1) ? NBKT_S : NBKT_S + NBKT_R;
    const int len = (ty == 0) ? NBKT_S : NBKT_R;
    const int t = threadIdx.x;
    const int own = (t < len) ? binTotal[start + t] : 0;
    s[t] = own;
    __syncthreads();
#pragma unroll
    for (int off = 1; off < 512; off <<= 1) {
        const int u = (t >= off) ? s[t - off] : 0;
        __syncthreads();
        s[t] += u;
        __syncthreads();
    }
    if (t < len) bucketStart[start + t] = s[t] - own;
}

__global__ __launch_bounds__(256) void scatA(
    const int* __restrict__ s0, const int* __restrict__ d0,
    const int* __restrict__ s1, const int* __restrict__ d1,
    const int* __restrict__ s2, const int* __restrict__ d2,
    const int* __restrict__ blkpfx, const int* __restrict__ bucketStart,
    unsigned* __restrict__ bktE)
{
    __shared__ int hist[NBKT_MAX];
    const int b = blockIdx.x;
    const int type = b / NB_A;
    const int blk = b - type * NB_A;
    const int nbkt = (type == 0) ? NBKT_S : NBKT_R;
    const int segStart = (type == 0) ? 0 : (type == 1) ? NBKT_S : NBKT_S + NBKT_R;
    const int* src = (type == 0) ? s0 : (type == 1) ? s1 : s2;
    const int* dst = (type == 0) ? d0 : (type == 1) ? d1 : d2;
    for (int i = threadIdx.x; i < nbkt; i += 256) hist[i] = 0;
    __syncthreads();
    const size_t rowBase = ((size_t)type * NB_A + blk) * NBKT_MAX;
    unsigned* bo = bktE + (size_t)type * NEDGE;
    const int e1 = min((blk + 1) * CHK, NEDGE);
    for (int e = blk * CHK + threadIdx.x; e < e1; e += 256) {
        const int d = dst[e];
        const int bin = d >> 8;
        const int lrank = atomicAdd(&hist[bin], 1);
        const int slot = bucketStart[segStart + bin] + blkpfx[rowBase + bin] + lrank;
        bo[slot] = (unsigned)src[e] | ((unsigned)(d & 255) << 24);
    }
}

__global__ __launch_bounds__(256) void phaseB(
    const unsigned* __restrict__ bktE, const int* __restrict__ bucketStart,
    const int* __restrict__ binTotal,
    int* __restrict__ offRev, int* __restrict__ offHr, int* __restrict__ offFc,
    int* __restrict__ csrRev, int* __restrict__ csrHr, int* __restrict__ csrFc,
    float* __restrict__ invS, float* __restrict__ invR, float* __restrict__ dis)
{
    __shared__ int cnt[256], cur[256], sc[256];
    const int gb = blockIdx.x;
    int type, bin, N;
    int *off, *csr;
    if (gb < NBKT_S)              { type = 0; bin = gb;                  N = NSUB; off = offRev; csr = csrRev; }
    else if (gb < NBKT_S + NBKT_R){ type = 1; bin = gb - NBKT_S;         N = NREG; off = offHr;  csr = csrHr; }
    else                          { type = 2; bin = gb - NBKT_S - NBKT_R;N = NREG; off = offFc;  csr = csrFc; }
    const int t = threadIdx.x;
    cnt[t] = 0; cur[t] = 0;
    __syncthreads();
    const int estart = bucketStart[gb];
    const int n = binTotal[gb];
    const unsigned* be = bktE + (size_t)type * NEDGE + estart;
    for (int j = t; j < n; j += 256) atomicAdd(&cnt[be[j] >> 24], 1);
    __syncthreads();
    const int own = cnt[t];
    sc[t] = own;
    __syncthreads();
#pragma unroll
    for (int off2 = 1; off2 < 256; off2 <<= 1) {
        const int u = (t >= off2) ? sc[t - off2] : 0;
        __syncthreads();
        sc[t] += u;
        __syncthreads();
    }
    const int excl = sc[t] - own;
    const int node = bin * 256 + t;
    if (node < N) {
        off[node + 1] = estart + sc[t];
        if (node == 0) off[0] = 0;
        if (type == 0)      invS[node] = 1.0f / fmaxf((float)own, 1.0f);
        else if (type == 1) invR[node] = 1.0f / fmaxf((float)own, 1.0f);
        else                dis[node]  = rsqrtf((float)(own + 1));   // +1 self loop
    }
    __syncthreads();
    cnt[t] = excl;
    __syncthreads();
    for (int j = t; j < n; j += 256) {
        const unsigned v = be[j];
        const int dl = v >> 24;
        const int slot = cnt[dl] + atomicAdd(&cur[dl], 1);
        csr[estart + slot] = (int)(v & 0x00FFFFFFu);
    }
}

// ---------------------------------------------------------------------------
// prep: input f32->bf16 conversion (blocks 0..CVT_BLKS) + weight packing.
// ---------------------------------------------------------------------------
__global__ void prep(const float* __restrict__ xs, const float* __restrict__ xr,
                     unsigned short* __restrict__ outS, unsigned short* __restrict__ outR,
                     const float* __restrict__ w0, const float* __restrict__ w1,
                     const float* __restrict__ w2, const float* __restrict__ w3,
                     const float* __restrict__ w4,
                     unsigned short* __restrict__ p0, unsigned short* __restrict__ p1,
                     unsigned short* __restrict__ p2, unsigned short* __restrict__ p3,
                     unsigned short* __restrict__ p4)
{
    const int b = blockIdx.x;
    if (b < CVT_BLKS) {
        const int i = b * 256 + threadIdx.x;
        const int nS = NSUB * DIM / 4;
        const float* in;
        unsigned short* out;
        int base;
        if (i < nS) { in = xs; out = outS; base = i * 4; }
        else        { in = xr; out = outR; base = (i - nS) * 4; }
        const float4 v = *(const float4*)(in + base);
        u16x4 o; o[0] = f2bf(v.x); o[1] = f2bf(v.y); o[2] = f2bf(v.z); o[3] = f2bf(v.w);
        *(u16x4*)(out + base) = o;
        return;
    }
    const int tid = (b - CVT_BLKS) * 256 + threadIdx.x;   // 5*LAY*2048 = 20480
    const int which = tid >> 12;
    const int rem = tid & 4095;
    const float* W = (which == 0) ? w0 : (which == 1) ? w1 : (which == 2) ? w2 : (which == 3) ? w3 : w4;
    unsigned short* P = (which == 0) ? p0 : (which == 1) ? p1 : (which == 2) ? p2 : (which == 3) ? p3 : p4;
    const int m = rem >> 11;
    const int rr = rem & 2047;
    const int f = rr >> 6, l = rr & 63;
    const int n0 = (f >> 2) * 16, k0 = (f & 3) * 32;
    const float* Wm = W + (size_t)m * DIM * DIM;
    unsigned short* Pm = P + (size_t)m * 32 * 512 + ((size_t)f * 64 + l) * 8;
    const int kb = k0 + (l >> 4) * 8, n = n0 + (l & 15);
#pragma unroll
    for (int j = 0; j < 8; ++j) Pm[j] = f2bf(Wm[(kb + j) * DIM + n]);
}

// ---------------------------------------------------------------------------
// Gathers: 16 lanes/row, u16x8/lane. r11: hoist the whole row's indices AND
// weights (up to 8, masked w=0 beyond degree) AHEAD of the value loads —
// removes the index->value dependent chain at burst boundaries. Value loads
// stay 4-deep to keep VGPR <= 64 (8 waves/SIMD occupancy).
// ---------------------------------------------------------------------------
__device__ __forceinline__ void gather_rows(
    const unsigned short* feat, const int* csr, int j, int j1, int c0,
    const float* wts, float acc[8])
{
    // burst prologue: covers degree <= 8 entirely (Poisson mean ~6)
    if (j < j1) {
        int s[8]; float w[8];
#pragma unroll
        for (int k = 0; k < 8; ++k) s[k] = csr[(j + k < j1) ? j + k : j];
#pragma unroll
        for (int k = 0; k < 8; ++k)
            w[k] = (j + k < j1) ? (wts ? wts[s[k]] : 1.0f) : 0.0f;
#pragma unroll
        for (int h = 0; h < 2; ++h) {                 // 2 half-bursts of 4 values
            u16x8 v0 = *(const u16x8*)(feat + (size_t)s[h * 4 + 0] * DIM + c0);
            u16x8 v1 = *(const u16x8*)(feat + (size_t)s[h * 4 + 1] * DIM + c0);
            u16x8 v2 = *(const u16x8*)(feat + (size_t)s[h * 4 + 2] * DIM + c0);
            u16x8 v3 = *(const u16x8*)(feat + (size_t)s[h * 4 + 3] * DIM + c0);
#pragma unroll
            for (int i = 0; i < 8; ++i)
                acc[i] += w[h * 4 + 0] * bf2f(v0[i]) + w[h * 4 + 1] * bf2f(v1[i]) +
                          w[h * 4 + 2] * bf2f(v2[i]) + w[h * 4 + 3] * bf2f(v3[i]);
        }
        j += 8;
    }
    // tail for degree > 8: proven 4-deep pipeline + singles
    for (; j + 4 <= j1; j += 4) {
        const int s0 = csr[j + 0], s1 = csr[j + 1], s2 = csr[j + 2], s3 = csr[j + 3];
        const u16x8 v0 = *(const u16x8*)(feat + (size_t)s0 * DIM + c0);
        const u16x8 v1 = *(const u16x8*)(feat + (size_t)s1 * DIM + c0);
        const u16x8 v2 = *(const u16x8*)(feat + (size_t)s2 * DIM + c0);
        const u16x8 v3 = *(const u16x8*)(feat + (size_t)s3 * DIM + c0);
        const float w0 = wts ? wts[s0] : 1.0f;
        const float w1 = wts ? wts[s1] : 1.0f;
        const float w2 = wts ? wts[s2] : 1.0f;
        const float w3 = wts ? wts[s3] : 1.0f;
#pragma unroll
        for (int i = 0; i < 8; ++i)
            acc[i] += w0 * bf2f(v0[i]) + w1 * bf2f(v1[i]) +
                      w2 * bf2f(v2[i]) + w3 * bf2f(v3[i]);
    }
    for (; j < j1; ++j) {
        const int s = csr[j];
        const u16x8 v = *(const u16x8*)(feat + (size_t)s * DIM + c0);
        const float w = wts ? wts[s] : 1.0f;
#pragma unroll
        for (int i = 0; i < 8; ++i) acc[i] += w * bf2f(v[i]);
    }
}

__global__ __launch_bounds__(256) void gather_all(
    const unsigned short* __restrict__ txS, const unsigned short* __restrict__ xr,
    const int* __restrict__ offHr, const int* __restrict__ csrHr, const float* __restrict__ invR,
    const int* __restrict__ offFc, const int* __restrict__ csrFc, const float* __restrict__ dis,
    const int* __restrict__ offRev, const int* __restrict__ csrRev, const float* __restrict__ invS,
    unsigned short* __restrict__ aggR, unsigned short* __restrict__ h,
    unsigned short* __restrict__ aggS)
{
    const int tid = blockIdx.x * 256 + threadIdx.x;
    const int g = tid >> 4;
    const int c0 = (tid & 15) * 8;
    if (g < NREG) {
        float acc[8] = {0, 0, 0, 0, 0, 0, 0, 0};
        gather_rows(txS, csrHr, offHr[g], offHr[g + 1], c0, nullptr, acc);
        const float sR = invR[g];
        u16x8 o;
#pragma unroll
        for (int i = 0; i < 8; ++i) o[i] = f2bf(acc[i] * sR);
        *(u16x8*)(aggR + (size_t)g * DIM + c0) = o;

        float a2[8] = {0, 0, 0, 0, 0, 0, 0, 0};
        gather_rows(xr, csrFc, offFc[g], offFc[g + 1], c0, dis, a2);
        const float dd = dis[g];
        const u16x8 sf = *(const u16x8*)(xr + (size_t)g * DIM + c0);
        u16x8 oh;
#pragma unroll
        for (int i = 0; i < 8; ++i) oh[i] = f2bf(dd * a2[i] + dd * dd * bf2f(sf[i]));
        *(u16x8*)(h + (size_t)g * DIM + c0) = oh;
    } else {
        const int gs = g - NREG;
        if (gs >= NSUB) return;
        float acc[8] = {0, 0, 0, 0, 0, 0, 0, 0};
        gather_rows(xr, csrRev, offRev[gs], offRev[gs + 1], c0, nullptr, acc);
        const float sS = invS[gs];
        u16x8 o;
#pragma unroll
        for (int i = 0; i < 8; ++i) o[i] = f2bf(acc[i] * sS);
        *(u16x8*)(aggS + (size_t)gs * DIM + c0) = o;
    }
}

// merged output projections
__global__ void lin2(const unsigned short* __restrict__ XS, const unsigned short* __restrict__ XR,
                     const float* __restrict__ Ws, const float* __restrict__ bs,
                     const float* __restrict__ Wr, const float* __restrict__ br,
                     float* __restrict__ out)
{
    const int r = blockIdx.x * 256 + threadIdx.x;
    if (r >= NSUB + NREG) return;
    const unsigned short* X;
    const float *W, *b;
    size_t row;
    if (r < NSUB) { X = XS; W = Ws; b = bs; row = r; }
    else          { X = XR; W = Wr; b = br; row = r - NSUB; }
    float a0 = b[0], a1 = b[1];
    const unsigned short* xp = X + row * DIM;
#pragma unroll
    for (int k = 0; k < DIM; k += 8) {
        const u16x8 v = *(const u16x8*)(xp + k);
#pragma unroll
        for (int i = 0; i < 8; ++i) {
            const float x = bf2f(v[i]);
            a0 += x * W[(k + i) * 2 + 0];
            a1 += x * W[(k + i) * 2 + 1];
        }
    }
    out[(size_t)r * 2 + 0] = a0;
    out[(size_t)r * 2 + 1] = a1;
}

extern "C" void kernel_launch(void* const* d_in, const int* in_sizes, int n_in,
                              void* d_out, int out_size, void* d_ws, size_t ws_size,
                              hipStream_t stream)
{
    const float* x_subject = (const float*)d_in[0];
    const float* x_region  = (const float*)d_in[1];
    const int*   ei_hr     = (const int*)d_in[2];
    const int*   ei_rev    = (const int*)d_in[3];
    const int*   ei_fc     = (const int*)d_in[4];
    const float* sr_Wl = (const float*)d_in[5];
    const float* sr_Wr = (const float*)d_in[6];
    const float* sr_b  = (const float*)d_in[7];
    const float* rs_Wl = (const float*)d_in[8];
    const float* rs_Wr = (const float*)d_in[9];
    const float* rs_b  = (const float*)d_in[10];
    const float* gcn_W = (const float*)d_in[11];
    const float* gcn_b = (const float*)d_in[12];
    const float* lsW   = (const float*)d_in[13];
    const float* lsb   = (const float*)d_in[14];
    const float* lrW   = (const float*)d_in[15];
    const float* lrb   = (const float*)d_in[16];

    // ---- workspace layout: f32 | bf16 | int32
    float* fp = (float*)d_ws;
    float* invS = fp; fp += NSUB;
    float* invR = fp; fp += NREG;
    float* dis  = fp; fp += NREG;
    unsigned short* up = (unsigned short*)fp;
    unsigned short* xsA  = up; up += (size_t)NSUB * DIM;
    unsigned short* xsB  = up; up += (size_t)NSUB * DIM;
    unsigned short* txS  = up; up += (size_t)NSUB * DIM;
    unsigned short* aggS = up; up += (size_t)NSUB * DIM;
    unsigned short* xrA  = up; up += (size_t)NREG * DIM;
    unsigned short* xrB  = up; up += (size_t)NREG * DIM;
    unsigned short* aggR = up; up += (size_t)NREG * DIM;
    unsigned short* h    = up; up += (size_t)NREG * DIM;
    unsigned short* pSrWl = up; up += (size_t)LAY * 16384;
    unsigned short* pSrWr = up; up += (size_t)LAY * 16384;
    unsigned short* pRsWl = up; up += (size_t)LAY * 16384;
    unsigned short* pRsWr = up; up += (size_t)LAY * 16384;
    unsigned short* pGcn  = up; up += (size_t)LAY * 16384;
    int* ip = (int*)up;
    int* offRev = ip; ip += NSUB + 1;
    int* offHr  = ip; ip += NREG + 1;
    int* offFc  = ip; ip += NREG + 2;   // pad
    int* csrRev = ip; ip += NEDGE;
    int* csrHr  = ip; ip += NEDGE;
    int* csrFc  = ip; ip += NEDGE;
    unsigned* bktE = (unsigned*)ip; ip += 3 * NEDGE;
    int* cntA   = ip; ip += 3 * NB_A * NBKT_MAX;
    int* blkpfx = ip; ip += 3 * NB_A * NBKT_MAX;
    int* binTotal = ip; ip += NBKT_TOT + 3;
    int* bucketStart = ip; ip += NBKT_TOT + 3;

    // ---- atomic-free CSR build (no memsets needed)
    histA<<<3 * NB_A, 256, 0, stream>>>(ei_rev + NEDGE, ei_hr + NEDGE, ei_fc + NEDGE, cntA);
    colscan<<<NBKT_TOT, NB_A, 0, stream>>>(cntA, blkpfx, binTotal);
    binscan<<<3, 512, 0, stream>>>(binTotal, bucketStart);
    scatA<<<3 * NB_A, 256, 0, stream>>>(ei_rev, ei_rev + NEDGE, ei_hr, ei_hr + NEDGE,
                                        ei_fc, ei_fc + NEDGE, blkpfx, bucketStart, bktE);
    phaseB<<<NBKT_TOT, 256, 0, stream>>>(bktE, bucketStart, binTotal,
                                         offRev, offHr, offFc, csrRev, csrHr, csrFc,
                                         invS, invR, dis);

    // ---- input conversion + weight packing (one dispatch)
    prep<<<CVT_BLKS + 80, 256, 0, stream>>>(x_subject, x_region, xsA, xrA,
                                            sr_Wl, sr_Wr, rs_Wl, rs_Wr, gcn_W,
                                            pSrWl, pSrWr, pRsWl, pRsWr, pGcn);

    const unsigned short* cxs = xsA;
    const unsigned short* cxr = xrA;
    unsigned short* nxs_l[2] = { xsB, xsA };
    unsigned short* nxr_l[2] = { xrB, xrA };
    const int SGB = (NSUB + 127) / 128;    // 157
    const int RGB = (NREG + 127) / 128;    // 782
    const int GA = ((NREG + NSUB) * 16) / 256;   // 7500

    for (int l = 0; l < LAY; ++l) {
        unsigned short* nxs = nxs_l[l];
        unsigned short* nxr = nxr_l[l];
        const size_t pOff = (size_t)l * 16384;
        const size_t bOff = (size_t)l * DIM;

        // 1) txS = xs @ sr_Wl   (transform-first for hr edges)
        gemm_fused<<<SGB, 256, 0, stream>>>(cxs, pSrWl + pOff, nullptr, nullptr,
                                            nullptr, nullptr, nullptr, txS, NSUB);
        // 2) aggR = invR*gather_hr(txS); h = GCN-aggregate(xr); aggS = invS*gather_rev(xr)
        gather_all<<<GA, 256, 0, stream>>>(txS, cxr, offHr, csrHr, invR,
                                           offFc, csrFc, dis, offRev, csrRev, invS,
                                           aggR, h, aggS);
        // 3+4) subject and region updates in one dispatch
        gemm_pair<<<SGB + RGB, 256, 0, stream>>>(
            cxs, pRsWr + pOff, aggS, pRsWl + pOff, rs_b + bOff, nxs, NSUB,
            cxr, pSrWr + pOff, h, pGcn + pOff, aggR, sr_b + bOff, gcn_b + bOff,
            nxr, NREG, SGB);
        cxs = nxs;
        cxr = nxr;
    }

    // ---- output projections
    lin2<<<(NSUB + NREG + 255) / 256, 256, 0, stream>>>(cxs, cxr, lsW, lsb, lrW, lrb,
                                                        (float*)d_out);
}

// Round 12
// 357.479 us; speedup vs baseline: 1.0065x; 1.0065x over previous
//
#include <hip/hip_runtime.h>

#define NSUB 20000
#define NREG 100000
#define NEDGE 600000
#define DIM 128
#define LAY 2
#define NOUT 2

// ---- atomic-free CSR build geometry ----
#define NB_A 256             // chunk blocks per edge type
#define CHK 2344             // ceil(NEDGE / NB_A)
#define NBKT_S 79            // subject coarse buckets (79*256 = 20224 >= NSUB)
#define NBKT_R 391           // region  coarse buckets (391*256 = 100096 >= NREG)
#define NBKT_MAX 391
#define NBKT_TOT (NBKT_S + 2 * NBKT_R)   // 861

#define CVT_BLKS 15000       // (NSUB+NREG)*DIM/4/256

typedef __attribute__((ext_vector_type(8))) short bf16x8;
typedef __attribute__((ext_vector_type(8))) unsigned short u16x8;
typedef __attribute__((ext_vector_type(4))) unsigned short u16x4;
typedef __attribute__((ext_vector_type(4))) float f32x4;

__device__ __forceinline__ float bf2f(unsigned short u) {
    return __uint_as_float(((unsigned)u) << 16);
}
__device__ __forceinline__ unsigned short f2bf(float f) {
    unsigned x = __float_as_uint(f);
    unsigned r = ((x >> 16) & 1u) + 0x7fffu;   // RNE
    return (unsigned short)((x + r) >> 16);
}

// ---------------------------------------------------------------------------
// MFMA GEMM body, 128-row tile (proven r6 structure).
// ---------------------------------------------------------------------------
__device__ __forceinline__ void gemm_body(
    const unsigned short* A0, const unsigned short* Wp0,
    const unsigned short* A1, const unsigned short* Wp1,
    const unsigned short* agg, const float* b0, const float* b1,
    unsigned short* out, int M, int rowBase, unsigned short* sO)
{
    const int t = threadIdx.x, wave = t >> 6, lane = t & 63;
    int ar0 = rowBase + wave * 32 + (lane & 15);
    int ar1 = ar0 + 16;
    if (ar0 >= M) ar0 = M - 1;
    if (ar1 >= M) ar1 = M - 1;
    const bf16x8* Ap0g0 = (const bf16x8*)(A0 + (size_t)ar0 * DIM + (lane >> 4) * 8);
    const bf16x8* Ap0g1 = (const bf16x8*)(A0 + (size_t)ar1 * DIM + (lane >> 4) * 8);
    const bf16x8* Bp0 = (const bf16x8*)Wp0;
    f32x4 acc[2][8] = {};
    if (A1) {
        const bf16x8* Ap1g0 = (const bf16x8*)(A1 + (size_t)ar0 * DIM + (lane >> 4) * 8);
        const bf16x8* Ap1g1 = (const bf16x8*)(A1 + (size_t)ar1 * DIM + (lane >> 4) * 8);
        const bf16x8* Bp1 = (const bf16x8*)Wp1;
#pragma unroll
        for (int ks = 0; ks < 4; ++ks) {
            const bf16x8 a00 = Ap0g0[ks * 4];
            const bf16x8 a01 = Ap0g1[ks * 4];
            const bf16x8 a10 = Ap1g0[ks * 4];
            const bf16x8 a11 = Ap1g1[ks * 4];
#pragma unroll
            for (int tn = 0; tn < 8; ++tn) {
                const bf16x8 bA = Bp0[(tn * 4 + ks) * 64 + lane];
                const bf16x8 bB = Bp1[(tn * 4 + ks) * 64 + lane];
                acc[0][tn] = __builtin_amdgcn_mfma_f32_16x16x32_bf16(a00, bA, acc[0][tn], 0, 0, 0);
                acc[1][tn] = __builtin_amdgcn_mfma_f32_16x16x32_bf16(a01, bA, acc[1][tn], 0, 0, 0);
                acc[0][tn] = __builtin_amdgcn_mfma_f32_16x16x32_bf16(a10, bB, acc[0][tn], 0, 0, 0);
                acc[1][tn] = __builtin_amdgcn_mfma_f32_16x16x32_bf16(a11, bB, acc[1][tn], 0, 0, 0);
            }
        }
    } else {
#pragma unroll
        for (int ks = 0; ks < 4; ++ks) {
            const bf16x8 a00 = Ap0g0[ks * 4];
            const bf16x8 a01 = Ap0g1[ks * 4];
#pragma unroll
            for (int tn = 0; tn < 8; ++tn) {
                const bf16x8 bA = Bp0[(tn * 4 + ks) * 64 + lane];
                acc[0][tn] = __builtin_amdgcn_mfma_f32_16x16x32_bf16(a00, bA, acc[0][tn], 0, 0, 0);
                acc[1][tn] = __builtin_amdgcn_mfma_f32_16x16x32_bf16(a01, bA, acc[1][tn], 0, 0, 0);
            }
        }
    }
    const int col0 = lane & 15;
#pragma unroll
    for (int g = 0; g < 2; ++g) {
        const int lrow0 = wave * 32 + g * 16 + (lane >> 4) * 4;
#pragma unroll
        for (int tn = 0; tn < 8; ++tn) {
            const int col = tn * 16 + col0;
            float bv = 0.0f;
            if (b0) bv += b0[col];
            if (b1) bv += b1[col];
#pragma unroll
            for (int r = 0; r < 4; ++r) {
                float v = acc[g][tn][r] + bv;
                if (agg) {
                    int rr = rowBase + lrow0 + r;
                    if (rr >= M) rr = M - 1;
                    v += bf2f(agg[(size_t)rr * DIM + col]);
                }
                sO[(lrow0 + r) * 132 + col] = f2bf(v);
            }
        }
    }
    __syncthreads();
#pragma unroll
    for (int p = 0; p < 2; ++p) {
        const int lr = p * 64 + (t >> 2), lc = (t & 3) * 32;
        const int grow = rowBase + lr;
        if (grow < M) {
            unsigned short* po = out + (size_t)grow * DIM + lc;
            const unsigned short* ps = sO + lr * 132 + lc;
#pragma unroll
            for (int j = 0; j < 8; ++j)
                *(u16x4*)(po + j * 4) = *(const u16x4*)(ps + j * 4);
        }
    }
}

__global__ __launch_bounds__(256) void gemm_fused(
    const unsigned short* __restrict__ A0, const unsigned short* __restrict__ Wp0,
    const unsigned short* __restrict__ A1, const unsigned short* __restrict__ Wp1,
    const unsigned short* __restrict__ agg,
    const float* __restrict__ b0, const float* __restrict__ b1,
    unsigned short* __restrict__ out, int M)
{
    __shared__ unsigned short sO[128 * 132];
    gemm_body(A0, Wp0, A1, Wp1, agg, b0, b1, out, M, blockIdx.x * 128, sO);
}

__global__ __launch_bounds__(256) void gemm_pair(
    const unsigned short* As0, const unsigned short* Ws0,
    const unsigned short* As1, const unsigned short* Ws1,
    const float* bs0, unsigned short* outS, int Ms,
    const unsigned short* Ar0, const unsigned short* Wr0,
    const unsigned short* Ar1, const unsigned short* Wr1,
    const unsigned short* aggr, const float* br0, const float* br1,
    unsigned short* outR, int Mr, int split)
{
    __shared__ unsigned short sO[128 * 132];
    const int bid = blockIdx.x;
    if (bid < split)
        gemm_body(As0, Ws0, As1, Ws1, nullptr, bs0, nullptr, outS, Ms, bid * 128, sO);
    else
        gemm_body(Ar0, Wr0, Ar1, Wr1, aggr, br0, br1, outR, Mr, (bid - split) * 128, sO);
}

// ---------------------------------------------------------------------------
// Atomic-free CSR build: two-level counting sort per edge type (r8 proven).
// ---------------------------------------------------------------------------
__global__ __launch_bounds__(256) void histA(
    const int* __restrict__ d0, const int* __restrict__ d1,
    const int* __restrict__ d2, int* __restrict__ cntA)
{
    __shared__ int hist[NBKT_MAX];
    const int b = blockIdx.x;
    const int type = b / NB_A;
    const int blk = b - type * NB_A;
    const int nbkt = (type == 0) ? NBKT_S : NBKT_R;
    const int* dst = (type == 0) ? d0 : (type == 1) ? d1 : d2;
    for (int i = threadIdx.x; i < nbkt; i += 256) hist[i] = 0;
    __syncthreads();
    const int e1 = min((blk + 1) * CHK, NEDGE);
    for (int e = blk * CHK + threadIdx.x; e < e1; e += 256)
        atomicAdd(&hist[dst[e] >> 8], 1);
    __syncthreads();
    int* row = cntA + ((size_t)type * NB_A + blk) * NBKT_MAX;
    for (int i = threadIdx.x; i < nbkt; i += 256) row[i] = hist[i];
}

__global__ __launch_bounds__(256) void colscan(
    const int* __restrict__ cntA, int* __restrict__ blkpfx, int* __restrict__ binTotal)
{
    __shared__ int s[NB_A];
    const int gb = blockIdx.x;
    int type, bin;
    if (gb < NBKT_S)              { type = 0; bin = gb; }
    else if (gb < NBKT_S + NBKT_R){ type = 1; bin = gb - NBKT_S; }
    else                          { type = 2; bin = gb - NBKT_S - NBKT_R; }
    const int t = threadIdx.x;
    const size_t idx = ((size_t)type * NB_A + t) * NBKT_MAX + bin;
    const int own = cntA[idx];
    s[t] = own;
    __syncthreads();
#pragma unroll
    for (int off = 1; off < NB_A; off <<= 1) {
        const int u = (t >= off) ? s[t - off] : 0;
        __syncthreads();
        s[t] += u;
        __syncthreads();
    }
    blkpfx[idx] = s[t] - own;
    if (t == NB_A - 1) binTotal[gb] = s[t];
}

__global__ void binscan(const int* __restrict__ binTotal, int* __restrict__ bucketStart)
{
    __shared__ int s[512];
    const int ty = blockIdx.x;
    const int start = (ty == 0) ? 0 : (ty == 1) ? NBKT_S : NBKT_S + NBKT_R;
    const int len = (ty == 0) ? NBKT_S : NBKT_R;
    const int t = threadIdx.x;
    const int own = (t < len) ? binTotal[start + t] : 0;
    s[t] = own;
    __syncthreads();
#pragma unroll
    for (int off = 1; off < 512; off <<= 1) {
        const int u = (t >= off) ? s[t - off] : 0;
        __syncthreads();
        s[t] += u;
        __syncthreads();
    }
    if (t < len) bucketStart[start + t] = s[t] - own;
}

__global__ __launch_bounds__(256) void scatA(
    const int* __restrict__ s0, const int* __restrict__ d0,
    const int* __restrict__ s1, const int* __restrict__ d1,
    const int* __restrict__ s2, const int* __restrict__ d2,
    const int* __restrict__ blkpfx, const int* __restrict__ bucketStart,
    unsigned* __restrict__ bktE)
{
    __shared__ int hist[NBKT_MAX];
    const int b = blockIdx.x;
    const int type = b / NB_A;
    const int blk = b - type * NB_A;
    const int nbkt = (type == 0) ? NBKT_S : NBKT_R;
    const int segStart = (type == 0) ? 0 : (type == 1) ? NBKT_S : NBKT_S + NBKT_R;
    const int* src = (type == 0) ? s0 : (type == 1) ? s1 : s2;
    const int* dst = (type == 0) ? d0 : (type == 1) ? d1 : d2;
    for (int i = threadIdx.x; i < nbkt; i += 256) hist[i] = 0;
    __syncthreads();
    const size_t rowBase = ((size_t)type * NB_A + blk) * NBKT_MAX;
    unsigned* bo = bktE + (size_t)type * NEDGE;
    const int e1 = min((blk + 1) * CHK, NEDGE);
    for (int e = blk * CHK + threadIdx.x; e < e1; e += 256) {
        const int d = dst[e];
        const int bin = d >> 8;
        const int lrank = atomicAdd(&hist[bin], 1);
        const int slot = bucketStart[segStart + bin] + blkpfx[rowBase + bin] + lrank;
        bo[slot] = (unsigned)src[e] | ((unsigned)(d & 255) << 24);
    }
}

__global__ __launch_bounds__(256) void phaseB(
    const unsigned* __restrict__ bktE, const int* __restrict__ bucketStart,
    const int* __restrict__ binTotal,
    int* __restrict__ offRev, int* __restrict__ offHr, int* __restrict__ offFc,
    int* __restrict__ csrRev, int* __restrict__ csrHr, int* __restrict__ csrFc,
    float* __restrict__ invS, float* __restrict__ invR, float* __restrict__ dis)
{
    __shared__ int cnt[256], cur[256], sc[256];
    const int gb = blockIdx.x;
    int type, bin, N;
    int *off, *csr;
    if (gb < NBKT_S)              { type = 0; bin = gb;                  N = NSUB; off = offRev; csr = csrRev; }
    else if (gb < NBKT_S + NBKT_R){ type = 1; bin = gb - NBKT_S;         N = NREG; off = offHr;  csr = csrHr; }
    else                          { type = 2; bin = gb - NBKT_S - NBKT_R;N = NREG; off = offFc;  csr = csrFc; }
    const int t = threadIdx.x;
    cnt[t] = 0; cur[t] = 0;
    __syncthreads();
    const int estart = bucketStart[gb];
    const int n = binTotal[gb];
    const unsigned* be = bktE + (size_t)type * NEDGE + estart;
    for (int j = t; j < n; j += 256) atomicAdd(&cnt[be[j] >> 24], 1);
    __syncthreads();
    const int own = cnt[t];
    sc[t] = own;
    __syncthreads();
#pragma unroll
    for (int off2 = 1; off2 < 256; off2 <<= 1) {
        const int u = (t >= off2) ? sc[t - off2] : 0;
        __syncthreads();
        sc[t] += u;
        __syncthreads();
    }
    const int excl = sc[t] - own;
    const int node = bin * 256 + t;
    if (node < N) {
        off[node + 1] = estart + sc[t];
        if (node == 0) off[0] = 0;
        if (type == 0)      invS[node] = 1.0f / fmaxf((float)own, 1.0f);
        else if (type == 1) invR[node] = 1.0f / fmaxf((float)own, 1.0f);
        else                dis[node]  = rsqrtf((float)(own + 1));   // +1 self loop
    }
    __syncthreads();
    cnt[t] = excl;
    __syncthreads();
    for (int j = t; j < n; j += 256) {
        const unsigned v = be[j];
        const int dl = v >> 24;
        const int slot = cnt[dl] + atomicAdd(&cur[dl], 1);
        csr[estart + slot] = (int)(v & 0x00FFFFFFu);
    }
}

// ---------------------------------------------------------------------------
// prep: input f32->bf16 conversion (blocks 0..CVT_BLKS) + weight packing.
// ---------------------------------------------------------------------------
__global__ void prep(const float* __restrict__ xs, const float* __restrict__ xr,
                     unsigned short* __restrict__ outS, unsigned short* __restrict__ outR,
                     const float* __restrict__ w0, const float* __restrict__ w1,
                     const float* __restrict__ w2, const float* __restrict__ w3,
                     const float* __restrict__ w4,
                     unsigned short* __restrict__ p0, unsigned short* __restrict__ p1,
                     unsigned short* __restrict__ p2, unsigned short* __restrict__ p3,
                     unsigned short* __restrict__ p4)
{
    const int b = blockIdx.x;
    if (b < CVT_BLKS) {
        const int i = b * 256 + threadIdx.x;
        const int nS = NSUB * DIM / 4;
        const float* in;
        unsigned short* out;
        int base;
        if (i < nS) { in = xs; out = outS; base = i * 4; }
        else        { in = xr; out = outR; base = (i - nS) * 4; }
        const float4 v = *(const float4*)(in + base);
        u16x4 o; o[0] = f2bf(v.x); o[1] = f2bf(v.y); o[2] = f2bf(v.z); o[3] = f2bf(v.w);
        *(u16x4*)(out + base) = o;
        return;
    }
    const int tid = (b - CVT_BLKS) * 256 + threadIdx.x;   // 5*LAY*2048 = 20480
    const int which = tid >> 12;
    const int rem = tid & 4095;
    const float* W = (which == 0) ? w0 : (which == 1) ? w1 : (which == 2) ? w2 : (which == 3) ? w3 : w4;
    unsigned short* P = (which == 0) ? p0 : (which == 1) ? p1 : (which == 2) ? p2 : (which == 3) ? p3 : p4;
    const int m = rem >> 11;
    const int rr = rem & 2047;
    const int f = rr >> 6, l = rr & 63;
    const int n0 = (f >> 2) * 16, k0 = (f & 3) * 32;
    const float* Wm = W + (size_t)m * DIM * DIM;
    unsigned short* Pm = P + (size_t)m * 32 * 512 + ((size_t)f * 64 + l) * 8;
    const int kb = k0 + (l >> 4) * 8, n = n0 + (l & 15);
#pragma unroll
    for (int j = 0; j < 8; ++j) Pm[j] = f2bf(Wm[(kb + j) * DIM + n]);
}

// ---------------------------------------------------------------------------
// Gathers (r8/r10-proven optimum): 16 lanes/row, u16x8/lane, 4-deep index
// pipeline. r9 (1 wave/row, 4B/lane) and r11 (8-deep hoisted burst) both
// regressed — this config is the empirical floor.
// ---------------------------------------------------------------------------
__device__ __forceinline__ void gather_rows(
    const unsigned short* feat, const int* csr, int j, int j1, int c0,
    const float* wts, float acc[8])
{
    for (; j + 4 <= j1; j += 4) {
        const int s0 = csr[j + 0], s1 = csr[j + 1], s2 = csr[j + 2], s3 = csr[j + 3];
        const u16x8 v0 = *(const u16x8*)(feat + (size_t)s0 * DIM + c0);
        const u16x8 v1 = *(const u16x8*)(feat + (size_t)s1 * DIM + c0);
        const u16x8 v2 = *(const u16x8*)(feat + (size_t)s2 * DIM + c0);
        const u16x8 v3 = *(const u16x8*)(feat + (size_t)s3 * DIM + c0);
        const float w0 = wts ? wts[s0] : 1.0f;
        const float w1 = wts ? wts[s1] : 1.0f;
        const float w2 = wts ? wts[s2] : 1.0f;
        const float w3 = wts ? wts[s3] : 1.0f;
#pragma unroll
        for (int i = 0; i < 8; ++i)
            acc[i] += w0 * bf2f(v0[i]) + w1 * bf2f(v1[i]) +
                      w2 * bf2f(v2[i]) + w3 * bf2f(v3[i]);
    }
    for (; j < j1; ++j) {
        const int s = csr[j];
        const u16x8 v = *(const u16x8*)(feat + (size_t)s * DIM + c0);
        const float w = wts ? wts[s] : 1.0f;
#pragma unroll
        for (int i = 0; i < 8; ++i) acc[i] += w * bf2f(v[i]);
    }
}

__global__ __launch_bounds__(256) void gather_all(
    const unsigned short* __restrict__ txS, const unsigned short* __restrict__ xr,
    const int* __restrict__ offHr, const int* __restrict__ csrHr, const float* __restrict__ invR,
    const int* __restrict__ offFc, const int* __restrict__ csrFc, const float* __restrict__ dis,
    const int* __restrict__ offRev, const int* __restrict__ csrRev, const float* __restrict__ invS,
    unsigned short* __restrict__ aggR, unsigned short* __restrict__ h,
    unsigned short* __restrict__ aggS)
{
    const int tid = blockIdx.x * 256 + threadIdx.x;
    const int g = tid >> 4;
    const int c0 = (tid & 15) * 8;
    if (g < NREG) {
        float acc[8] = {0, 0, 0, 0, 0, 0, 0, 0};
        gather_rows(txS, csrHr, offHr[g], offHr[g + 1], c0, nullptr, acc);
        const float sR = invR[g];
        u16x8 o;
#pragma unroll
        for (int i = 0; i < 8; ++i) o[i] = f2bf(acc[i] * sR);
        *(u16x8*)(aggR + (size_t)g * DIM + c0) = o;

        float a2[8] = {0, 0, 0, 0, 0, 0, 0, 0};
        gather_rows(xr, csrFc, offFc[g], offFc[g + 1], c0, dis, a2);
        const float dd = dis[g];
        const u16x8 sf = *(const u16x8*)(xr + (size_t)g * DIM + c0);
        u16x8 oh;
#pragma unroll
        for (int i = 0; i < 8; ++i) oh[i] = f2bf(dd * a2[i] + dd * dd * bf2f(sf[i]));
        *(u16x8*)(h + (size_t)g * DIM + c0) = oh;
    } else {
        const int gs = g - NREG;
        if (gs >= NSUB) return;
        float acc[8] = {0, 0, 0, 0, 0, 0, 0, 0};
        gather_rows(xr, csrRev, offRev[gs], offRev[gs + 1], c0, nullptr, acc);
        const float sS = invS[gs];
        u16x8 o;
#pragma unroll
        for (int i = 0; i < 8; ++i) o[i] = f2bf(acc[i] * sS);
        *(u16x8*)(aggS + (size_t)gs * DIM + c0) = o;
    }
}

// merged output projections
__global__ void lin2(const unsigned short* __restrict__ XS, const unsigned short* __restrict__ XR,
                     const float* __restrict__ Ws, const float* __restrict__ bs,
                     const float* __restrict__ Wr, const float* __restrict__ br,
                     float* __restrict__ out)
{
    const int r = blockIdx.x * 256 + threadIdx.x;
    if (r >= NSUB + NREG) return;
    const unsigned short* X;
    const float *W, *b;
    size_t row;
    if (r < NSUB) { X = XS; W = Ws; b = bs; row = r; }
    else          { X = XR; W = Wr; b = br; row = r - NSUB; }
    float a0 = b[0], a1 = b[1];
    const unsigned short* xp = X + row * DIM;
#pragma unroll
    for (int k = 0; k < DIM; k += 8) {
        const u16x8 v = *(const u16x8*)(xp + k);
#pragma unroll
        for (int i = 0; i < 8; ++i) {
            const float x = bf2f(v[i]);
            a0 += x * W[(k + i) * 2 + 0];
            a1 += x * W[(k + i) * 2 + 1];
        }
    }
    out[(size_t)r * 2 + 0] = a0;
    out[(size_t)r * 2 + 1] = a1;
}

extern "C" void kernel_launch(void* const* d_in, const int* in_sizes, int n_in,
                              void* d_out, int out_size, void* d_ws, size_t ws_size,
                              hipStream_t stream)
{
    const float* x_subject = (const float*)d_in[0];
    const float* x_region  = (const float*)d_in[1];
    const int*   ei_hr     = (const int*)d_in[2];
    const int*   ei_rev    = (const int*)d_in[3];
    const int*   ei_fc     = (const int*)d_in[4];
    const float* sr_Wl = (const float*)d_in[5];
    const float* sr_Wr = (const float*)d_in[6];
    const float* sr_b  = (const float*)d_in[7];
    const float* rs_Wl = (const float*)d_in[8];
    const float* rs_Wr = (const float*)d_in[9];
    const float* rs_b  = (const float*)d_in[10];
    const float* gcn_W = (const float*)d_in[11];
    const float* gcn_b = (const float*)d_in[12];
    const float* lsW   = (const float*)d_in[13];
    const float* lsb   = (const float*)d_in[14];
    const float* lrW   = (const float*)d_in[15];
    const float* lrb   = (const float*)d_in[16];

    // ---- workspace layout: f32 | bf16 | int32
    float* fp = (float*)d_ws;
    float* invS = fp; fp += NSUB;
    float* invR = fp; fp += NREG;
    float* dis  = fp; fp += NREG;
    unsigned short* up = (unsigned short*)fp;
    unsigned short* xsA  = up; up += (size_t)NSUB * DIM;
    unsigned short* xsB  = up; up += (size_t)NSUB * DIM;
    unsigned short* txS  = up; up += (size_t)NSUB * DIM;
    unsigned short* aggS = up; up += (size_t)NSUB * DIM;
    unsigned short* xrA  = up; up += (size_t)NREG * DIM;
    unsigned short* xrB  = up; up += (size_t)NREG * DIM;
    unsigned short* aggR = up; up += (size_t)NREG * DIM;
    unsigned short* h    = up; up += (size_t)NREG * DIM;
    unsigned short* pSrWl = up; up += (size_t)LAY * 16384;
    unsigned short* pSrWr = up; up += (size_t)LAY * 16384;
    unsigned short* pRsWl = up; up += (size_t)LAY * 16384;
    unsigned short* pRsWr = up; up += (size_t)LAY * 16384;
    unsigned short* pGcn  = up; up += (size_t)LAY * 16384;
    int* ip = (int*)up;
    int* offRev = ip; ip += NSUB + 1;
    int* offHr  = ip; ip += NREG + 1;
    int* offFc  = ip; ip += NREG + 2;   // pad
    int* csrRev = ip; ip += NEDGE;
    int* csrHr  = ip; ip += NEDGE;
    int* csrFc  = ip; ip += NEDGE;
    unsigned* bktE = (unsigned*)ip; ip += 3 * NEDGE;
    int* cntA   = ip; ip += 3 * NB_A * NBKT_MAX;
    int* blkpfx = ip; ip += 3 * NB_A * NBKT_MAX;
    int* binTotal = ip; ip += NBKT_TOT + 3;
    int* bucketStart = ip; ip += NBKT_TOT + 3;

    // ---- atomic-free CSR build (no memsets needed)
    histA<<<3 * NB_A, 256, 0, stream>>>(ei_rev + NEDGE, ei_hr + NEDGE, ei_fc + NEDGE, cntA);
    colscan<<<NBKT_TOT, NB_A, 0, stream>>>(cntA, blkpfx, binTotal);
    binscan<<<3, 512, 0, stream>>>(binTotal, bucketStart);
    scatA<<<3 * NB_A, 256, 0, stream>>>(ei_rev, ei_rev + NEDGE, ei_hr, ei_hr + NEDGE,
                                        ei_fc, ei_fc + NEDGE, blkpfx, bucketStart, bktE);
    phaseB<<<NBKT_TOT, 256, 0, stream>>>(bktE, bucketStart, binTotal,
                                         offRev, offHr, offFc, csrRev, csrHr, csrFc,
                                         invS, invR, dis);

    // ---- input conversion + weight packing (one dispatch)
    prep<<<CVT_BLKS + 80, 256, 0, stream>>>(x_subject, x_region, xsA, xrA,
                                            sr_Wl, sr_Wr, rs_Wl, rs_Wr, gcn_W,
                                            pSrWl, pSrWr, pRsWl, pRsWr, pGcn);

    const unsigned short* cxs = xsA;
    const unsigned short* cxr = xrA;
    unsigned short* nxs_l[2] = { xsB, xsA };
    unsigned short* nxr_l[2] = { xrB, xrA };
    const int SGB = (NSUB + 127) / 128;    // 157
    const int RGB = (NREG + 127) / 128;    // 782
    const int GA = ((NREG + NSUB) * 16) / 256;   // 7500

    for (int l = 0; l < LAY; ++l) {
        unsigned short* nxs = nxs_l[l];
        unsigned short* nxr = nxr_l[l];
        const size_t pOff = (size_t)l * 16384;
        const size_t bOff = (size_t)l * DIM;

        // 1) txS = xs @ sr_Wl   (transform-first for hr edges)
        gemm_fused<<<SGB, 256, 0, stream>>>(cxs, pSrWl + pOff, nullptr, nullptr,
                                            nullptr, nullptr, nullptr, txS, NSUB);
        // 2) aggR = invR*gather_hr(txS); h = GCN-aggregate(xr); aggS = invS*gather_rev(xr)
        gather_all<<<GA, 256, 0, stream>>>(txS, cxr, offHr, csrHr, invR,
                                           offFc, csrFc, dis, offRev, csrRev, invS,
                                           aggR, h, aggS);
        // 3+4) subject and region updates in one dispatch
        gemm_pair<<<SGB + RGB, 256, 0, stream>>>(
            cxs, pRsWr + pOff, aggS, pRsWl + pOff, rs_b + bOff, nxs, NSUB,
            cxr, pSrWr + pOff, h, pGcn + pOff, aggR, sr_b + bOff, gcn_b + bOff,
            nxr, NREG, SGB);
        cxs = nxs;
        cxr = nxr;
    }

    // ---- output projections
    lin2<<<(NSUB + NREG + 255) / 256, 256, 0, stream>>>(cxs, cxr, lsW, lsb, lrW, lrb,
                                                        (float*)d_out);
}